// Round 1
// baseline (412.272 us; speedup 1.0000x reference)
//
#include <hip/hip_runtime.h>
#include <cfloat>
#include <cmath>

#define NN 8192
#define DD 16
#define KMAX 20
#define EPSF 1e-8f
#define TJ 256

typedef float4 f4;

// float4-quad XOR swizzle: spreads b128 LDS reads of row-major [256][16] f32
// uniformly over the 8 aligned 16B bank-groups (verified: bank-quad =
// 4*(j&1) + (q ^ ((j>>1)&3)) covers all 8 values over j mod 8).
__device__ __forceinline__ int swzi(int j, int q) { return (j << 2) | (q ^ ((j >> 1) & 3)); }

// ---------------- Kernel A: column mean/std(ddof=1) of x ----------------
__global__ __launch_bounds__(1024) void k_colstats_x(const float* __restrict__ x,
                                                     float* __restrict__ mean,
                                                     float* __restrict__ stdx) {
    const int tid = threadIdx.x;
    double s[DD], s2[DD];
#pragma unroll
    for (int c = 0; c < DD; c++) { s[c] = 0.0; s2[c] = 0.0; }
    for (int r = tid; r < NN; r += 1024) {
        const f4* xr = (const f4*)(x + (size_t)r * DD);
#pragma unroll
        for (int q = 0; q < 4; q++) {
            f4 v = xr[q];
            double a;
            a = v.x; s[4*q+0] += a; s2[4*q+0] += a * a;
            a = v.y; s[4*q+1] += a; s2[4*q+1] += a * a;
            a = v.z; s[4*q+2] += a; s2[4*q+2] += a * a;
            a = v.w; s[4*q+3] += a; s2[4*q+3] += a * a;
        }
    }
#pragma unroll
    for (int c = 0; c < DD; c++) {
#pragma unroll
        for (int off = 1; off < 64; off <<= 1) {
            s[c] += __shfl_xor(s[c], off);
            s2[c] += __shfl_xor(s2[c], off);
        }
    }
    __shared__ double red[16][2 * DD];
    const int wid = tid >> 6, lane = tid & 63;
    if (lane == 0) {
#pragma unroll
        for (int c = 0; c < DD; c++) { red[wid][c] = s[c]; red[wid][DD + c] = s2[c]; }
    }
    __syncthreads();
    if (tid < 2 * DD) {
        double t = 0.0;
        for (int w = 0; w < 16; w++) t += red[w][tid];
        red[0][tid] = t;  // each thread only rewrites its own column
    }
    __syncthreads();
    if (tid < DD) {
        double sm = red[0][tid], sq = red[0][DD + tid];
        double mu = sm / (double)NN;
        double var = (sq - sm * sm / (double)NN) / (double)(NN - 1);
        mean[tid] = (float)mu;
        stdx[tid] = (float)sqrt(var > 0.0 ? var : 0.0);
    }
}

// ---------------- Kernel B: xc = x - mean, sq[i] = ||xc_i||^2 ----------------
__global__ __launch_bounds__(256) void k_center(const float* __restrict__ x,
                                                const float* __restrict__ meanp,
                                                float* __restrict__ xc,
                                                float* __restrict__ sq) {
    const int i = blockIdx.x * 256 + threadIdx.x;
    const f4* mr = (const f4*)meanp;
    const f4* xr = (const f4*)(x + (size_t)i * DD);
    f4* xo = (f4*)(xc + (size_t)i * DD);
    float s = 0.f;
#pragma unroll
    for (int q = 0; q < 4; q++) {
        f4 m = mr[q];
        f4 v = xr[q];
        v.x -= m.x; v.y -= m.y; v.z -= m.z; v.w -= m.w;
        s += v.x * v.x + v.y * v.y + v.z * v.z + v.w * v.w;
        xo[q] = v;
    }
    sq[i] = s;
}

// ---------------- Kernel C: per-row dist sum/sum2 (density) + exact top-20 ----------------
__global__ __launch_bounds__(256) void k_density_topk(const float* __restrict__ xc,
                                                      const float* __restrict__ sq,
                                                      float* __restrict__ density,
                                                      float* __restrict__ smallest) {
    __shared__ f4 tile[TJ * 4];
    __shared__ float sqs[TJ];
    __shared__ float lists[4][64][KMAX];
    const int tid = threadIdx.x;
    const int wid = tid >> 6, lane = tid & 63;
    const int i = blockIdx.x * 4 + wid;

    const f4* xir = (const f4*)(xc + (size_t)i * DD);
    f4 xi0 = xir[0], xi1 = xir[1], xi2 = xir[2], xi3 = xir[3];
    const float sqi = sq[i];

    double ds1 = 0.0, ds2 = 0.0;
    float lst[KMAX];
#pragma unroll
    for (int c = 0; c < KMAX; c++) lst[c] = FLT_MAX;

    for (int tb = 0; tb < NN; tb += TJ) {
        {
            const f4* src = (const f4*)(xc + (size_t)(tb + tid) * DD);
#pragma unroll
            for (int q = 0; q < 4; q++) tile[swzi(tid, q)] = src[q];
            sqs[tid] = sq[tb + tid];
        }
        __syncthreads();
#pragma unroll
        for (int r = 0; r < 4; r++) {
            const int jl = lane + 64 * r;
            f4 a0 = tile[swzi(jl, 0)], a1 = tile[swzi(jl, 1)];
            f4 a2 = tile[swzi(jl, 2)], a3 = tile[swzi(jl, 3)];
            float dot = a0.x * xi0.x + a0.y * xi0.y + a0.z * xi0.z + a0.w * xi0.w
                      + a1.x * xi1.x + a1.y * xi1.y + a1.z * xi1.z + a1.w * xi1.w
                      + a2.x * xi2.x + a2.y * xi2.y + a2.z * xi2.z + a2.w * xi2.w
                      + a3.x * xi3.x + a3.y * xi3.y + a3.z * xi3.z + a3.w * xi3.w;
            float d2 = sqi + sqs[jl] - 2.0f * dot;
            float d = sqrtf(fmaxf(d2, 0.0f));
            ds1 += (double)d;
            ds2 += (double)d * (double)d;
            if (d < lst[KMAX - 1]) {  // sorted-insert network, static indices only
                float cur = d;
#pragma unroll
                for (int c = 0; c < KMAX; c++) {
                    float lo = fminf(lst[c], cur);
                    float hi = fmaxf(lst[c], cur);
                    lst[c] = lo;
                    cur = hi;
                }
            }
        }
        __syncthreads();
    }
    // density (row std, ddof=1)
#pragma unroll
    for (int off = 1; off < 64; off <<= 1) {
        ds1 += __shfl_xor(ds1, off);
        ds2 += __shfl_xor(ds2, off);
    }
    if (lane == 0) {
        double var = (ds2 - ds1 * ds1 / (double)NN) / (double)(NN - 1);
        density[i] = (float)sqrt(var > 0.0 ? var : 0.0);
    }
    // merge 64 sorted lists -> global 20 smallest via 20 rounds of wave argmin
#pragma unroll
    for (int c = 0; c < KMAX; c++) lists[wid][lane][c] = lst[c];
    __syncthreads();
    int idx = 0;
    for (int r = 0; r < KMAX; r++) {
        float cand = (idx < KMAX) ? lists[wid][lane][idx] : FLT_MAX;
        float m = cand;
#pragma unroll
        for (int off = 1; off < 64; off <<= 1) m = fminf(m, __shfl_xor(m, off));
        unsigned long long b = __ballot(cand == m);
        if (lane == (int)(__ffsll((unsigned long long)b) - 1)) idx++;
        if (lane == 0) smallest[(size_t)i * KMAX + r] = m;
    }
}

// ---------------- Kernel F: global adaptive k ----------------
__global__ __launch_bounds__(1024) void k_adaptk(const float* __restrict__ density,
                                                 int* __restrict__ kout) {
    const int tid = threadIdx.x;
    __shared__ float redf[16];
    __shared__ int redi[16];
    __shared__ float dmax_sh;
    const int wid = tid >> 6, lane = tid & 63;
    float mx = 0.f;
    for (int r = tid; r < NN; r += 1024) mx = fmaxf(mx, density[r]);
#pragma unroll
    for (int off = 1; off < 64; off <<= 1) mx = fmaxf(mx, __shfl_xor(mx, off));
    if (lane == 0) redf[wid] = mx;
    __syncthreads();
    if (tid == 0) {
        float m = redf[0];
        for (int w = 1; w < 16; w++) m = fmaxf(m, redf[w]);
        dmax_sh = m;
    }
    __syncthreads();
    const float dmax = dmax_sh + EPSF;
    int ks = 0;
    for (int r = tid; r < NN; r += 1024) {
        float f = density[r] / dmax;
        float kf = fminf(fmaxf(5.0f + 10.0f * f, 5.0f), 20.0f);
        ks += (int)kf;  // trunc toward zero, matches .astype(int32)
    }
#pragma unroll
    for (int off = 1; off < 64; off <<= 1) ks += __shfl_xor(ks, off);
    if (lane == 0) redi[wid] = ks;
    __syncthreads();
    if (tid == 0) {
        int t = 0;
        for (int w = 0; w < 16; w++) t += redi[w];
        float meank = (float)t / (float)NN;
        kout[0] = (int)meank;
    }
}

// ---------------- Kernel E: sigma -> kernel weights -> drift ----------------
__global__ __launch_bounds__(256) void k_drift(const float* __restrict__ xc,
                                               const float* __restrict__ sq,
                                               const float* __restrict__ smallest,
                                               const int* __restrict__ kptr,
                                               float* __restrict__ drift) {
    __shared__ f4 tile[TJ * 4];
    __shared__ float sqs[TJ];
    const int tid = threadIdx.x;
    const int wid = tid >> 6, lane = tid & 63;
    const int i = blockIdx.x * 4 + wid;

    const int k = kptr[0];
    const float sigma = smallest[(size_t)i * KMAX + (k - 1)];
    const float ninv = -1.0f / (2.0f * sigma * sigma + EPSF);

    const f4* xir = (const f4*)(xc + (size_t)i * DD);
    f4 xi0 = xir[0], xi1 = xir[1], xi2 = xir[2], xi3 = xir[3];
    const float sqi = sq[i];

    float wsum = 0.f;
    f4 dr0 = {0, 0, 0, 0}, dr1 = {0, 0, 0, 0}, dr2 = {0, 0, 0, 0}, dr3 = {0, 0, 0, 0};

    for (int tb = 0; tb < NN; tb += TJ) {
        {
            const f4* src = (const f4*)(xc + (size_t)(tb + tid) * DD);
#pragma unroll
            for (int q = 0; q < 4; q++) tile[swzi(tid, q)] = src[q];
            sqs[tid] = sq[tb + tid];
        }
        __syncthreads();
#pragma unroll
        for (int r = 0; r < 4; r++) {
            const int jl = lane + 64 * r;
            f4 a0 = tile[swzi(jl, 0)], a1 = tile[swzi(jl, 1)];
            f4 a2 = tile[swzi(jl, 2)], a3 = tile[swzi(jl, 3)];
            float dot = a0.x * xi0.x + a0.y * xi0.y + a0.z * xi0.z + a0.w * xi0.w
                      + a1.x * xi1.x + a1.y * xi1.y + a1.z * xi1.z + a1.w * xi1.w
                      + a2.x * xi2.x + a2.y * xi2.y + a2.z * xi2.z + a2.w * xi2.w
                      + a3.x * xi3.x + a3.y * xi3.y + a3.z * xi3.z + a3.w * xi3.w;
            float d2 = sqi + sqs[jl] - 2.0f * dot;
            float d = sqrtf(fmaxf(d2, 0.0f));
            float w = __expf(d * ninv);
            wsum += w;
            dr0.x += w * a0.x; dr0.y += w * a0.y; dr0.z += w * a0.z; dr0.w += w * a0.w;
            dr1.x += w * a1.x; dr1.y += w * a1.y; dr1.z += w * a1.z; dr1.w += w * a1.w;
            dr2.x += w * a2.x; dr2.y += w * a2.y; dr2.z += w * a2.z; dr2.w += w * a2.w;
            dr3.x += w * a3.x; dr3.y += w * a3.y; dr3.z += w * a3.z; dr3.w += w * a3.w;
        }
        __syncthreads();
    }
#pragma unroll
    for (int off = 1; off < 64; off <<= 1) {
        wsum += __shfl_xor(wsum, off);
        dr0.x += __shfl_xor(dr0.x, off); dr0.y += __shfl_xor(dr0.y, off);
        dr0.z += __shfl_xor(dr0.z, off); dr0.w += __shfl_xor(dr0.w, off);
        dr1.x += __shfl_xor(dr1.x, off); dr1.y += __shfl_xor(dr1.y, off);
        dr1.z += __shfl_xor(dr1.z, off); dr1.w += __shfl_xor(dr1.w, off);
        dr2.x += __shfl_xor(dr2.x, off); dr2.y += __shfl_xor(dr2.y, off);
        dr2.z += __shfl_xor(dr2.z, off); dr2.w += __shfl_xor(dr2.w, off);
        dr3.x += __shfl_xor(dr3.x, off); dr3.y += __shfl_xor(dr3.y, off);
        dr3.z += __shfl_xor(dr3.z, off); dr3.w += __shfl_xor(dr3.w, off);
    }
    if (lane == 0) {
        const float inv = 1.0f / (wsum + EPSF);
        f4* out = (f4*)(drift + (size_t)i * DD);
        f4 o0 = {dr0.x * inv, dr0.y * inv, dr0.z * inv, dr0.w * inv};
        f4 o1 = {dr1.x * inv, dr1.y * inv, dr1.z * inv, dr1.w * inv};
        f4 o2 = {dr2.x * inv, dr2.y * inv, dr2.z * inv, dr2.w * inv};
        f4 o3 = {dr3.x * inv, dr3.y * inv, dr3.z * inv, dr3.w * inv};
        out[0] = o0; out[1] = o1; out[2] = o2; out[3] = o3;
    }
}

// ---------------- Kernel G1: h_pre = xc + step*(drift - xc) + 0.01*noise ----------------
__global__ __launch_bounds__(256) void k_hpre(const float* __restrict__ xc,
                                              const float* __restrict__ drift,
                                              const float* __restrict__ noise,
                                              const float* __restrict__ alpha,
                                              float* __restrict__ hpre) {
    const int i = blockIdx.x * 256 + threadIdx.x;
    const float step = powf(16.0f, -alpha[0]);
    const f4* xr = (const f4*)(xc + (size_t)i * DD);
    const f4* dr = (const f4*)(drift + (size_t)i * DD);
    const f4* nr = (const f4*)(noise + (size_t)i * DD);
    f4* ho = (f4*)(hpre + (size_t)i * DD);
#pragma unroll
    for (int q = 0; q < 4; q++) {
        f4 a = xr[q], b = dr[q], n = nr[q], o;
        o.x = a.x + step * (b.x - a.x) + n.x * 0.01f;
        o.y = a.y + step * (b.y - a.y) + n.y * 0.01f;
        o.z = a.z + step * (b.z - a.z) + n.z * 0.01f;
        o.w = a.w + step * (b.w - a.w) + n.w * 0.01f;
        ho[q] = o;
    }
}

// ---------------- Kernel G2: column std of h_pre -> ratio = stdx/(stdh+eps) ----------------
__global__ __launch_bounds__(1024) void k_colstats_h(const float* __restrict__ h,
                                                     const float* __restrict__ stdx,
                                                     float* __restrict__ ratio) {
    const int tid = threadIdx.x;
    double s[DD], s2[DD];
#pragma unroll
    for (int c = 0; c < DD; c++) { s[c] = 0.0; s2[c] = 0.0; }
    for (int r = tid; r < NN; r += 1024) {
        const f4* xr = (const f4*)(h + (size_t)r * DD);
#pragma unroll
        for (int q = 0; q < 4; q++) {
            f4 v = xr[q];
            double a;
            a = v.x; s[4*q+0] += a; s2[4*q+0] += a * a;
            a = v.y; s[4*q+1] += a; s2[4*q+1] += a * a;
            a = v.z; s[4*q+2] += a; s2[4*q+2] += a * a;
            a = v.w; s[4*q+3] += a; s2[4*q+3] += a * a;
        }
    }
#pragma unroll
    for (int c = 0; c < DD; c++) {
#pragma unroll
        for (int off = 1; off < 64; off <<= 1) {
            s[c] += __shfl_xor(s[c], off);
            s2[c] += __shfl_xor(s2[c], off);
        }
    }
    __shared__ double red[16][2 * DD];
    const int wid = tid >> 6, lane = tid & 63;
    if (lane == 0) {
#pragma unroll
        for (int c = 0; c < DD; c++) { red[wid][c] = s[c]; red[wid][DD + c] = s2[c]; }
    }
    __syncthreads();
    if (tid < 2 * DD) {
        double t = 0.0;
        for (int w = 0; w < 16; w++) t += red[w][tid];
        red[0][tid] = t;
    }
    __syncthreads();
    if (tid < DD) {
        double sm = red[0][tid], sq = red[0][DD + tid];
        double var = (sq - sm * sm / (double)NN) / (double)(NN - 1);
        float stdh = (float)sqrt(var > 0.0 ? var : 0.0);
        ratio[tid] = stdx[tid] / (stdh + EPSF);
    }
}

// ---------------- Kernel G3: out = h_pre * ratio + mean (in place) ----------------
__global__ __launch_bounds__(256) void k_final(float* __restrict__ h,
                                               const float* __restrict__ ratio,
                                               const float* __restrict__ meanp) {
    const int i = blockIdx.x * 256 + threadIdx.x;
    const f4* rr = (const f4*)ratio;
    const f4* mr = (const f4*)meanp;
    f4* hr = (f4*)(h + (size_t)i * DD);
#pragma unroll
    for (int q = 0; q < 4; q++) {
        f4 v = hr[q], rv = rr[q], mv = mr[q];
        v.x = v.x * rv.x + mv.x;
        v.y = v.y * rv.y + mv.y;
        v.z = v.z * rv.z + mv.z;
        v.w = v.w * rv.w + mv.w;
        hr[q] = v;
    }
}

extern "C" void kernel_launch(void* const* d_in, const int* in_sizes, int n_in,
                              void* d_out, int out_size, void* d_ws, size_t ws_size,
                              hipStream_t stream) {
    (void)in_sizes; (void)n_in; (void)out_size; (void)ws_size;
    const float* x = (const float*)d_in[0];
    const float* noise = (const float*)d_in[1];
    const float* alpha = (const float*)d_in[2];
    float* out = (float*)d_out;

    float* ws = (float*)d_ws;
    float* xc    = ws;                         // N*D
    float* sq    = xc + (size_t)NN * DD;       // N
    float* den   = sq + NN;                    // N
    float* sml   = den + NN;                   // N*KMAX
    float* drf   = sml + (size_t)NN * KMAX;    // N*D
    float* meanp = drf + (size_t)NN * DD;      // 16
    float* stdx  = meanp + DD;                 // 16
    float* ratio = stdx + DD;                  // 16
    int*   kptr  = (int*)(ratio + DD);         // 1

    k_colstats_x<<<1, 1024, 0, stream>>>(x, meanp, stdx);
    k_center<<<NN / 256, 256, 0, stream>>>(x, meanp, xc, sq);
    k_density_topk<<<NN / 4, 256, 0, stream>>>(xc, sq, den, sml);
    k_adaptk<<<1, 1024, 0, stream>>>(den, kptr);
    k_drift<<<NN / 4, 256, 0, stream>>>(xc, sq, sml, kptr, drf);
    k_hpre<<<NN / 256, 256, 0, stream>>>(xc, drf, noise, alpha, out);
    k_colstats_h<<<1, 1024, 0, stream>>>(out, stdx, ratio);
    k_final<<<NN / 256, 256, 0, stream>>>(out, ratio, meanp);
}

// Round 2
// 283.752 us; speedup vs baseline: 1.4529x; 1.4529x over previous
//
#include <hip/hip_runtime.h>
#include <hip/hip_fp16.h>
#include <cfloat>
#include <cmath>
#include <cstdint>

#define NN 8192
#define DD 16
#define KCAP 15      // k = int(mean(clip(5+10f,5,20))) with f in [0,1] -> k in [5,15]
#define EPSF 1e-8f
#define TJ 512
#define RPB 8        // rows per block (1 per wave, 512-thread blocks)

typedef float4 f4;
typedef _Float16 h2v __attribute__((ext_vector_type(2)));

__device__ __forceinline__ float fdot2a(uint32_t a, uint32_t b, float c) {
#if defined(__has_builtin) && __has_builtin(__builtin_amdgcn_fdot2)
    return __builtin_amdgcn_fdot2(__builtin_bit_cast(h2v, a), __builtin_bit_cast(h2v, b), c, false);
#else
    __half2 ah = __builtin_bit_cast(__half2, a), bh = __builtin_bit_cast(__half2, b);
    float2 af = __half22float2(ah), bf = __half22float2(bh);
    return fmaf(af.x, bf.x, fmaf(af.y, bf.y, c));
#endif
}

__device__ __forceinline__ unsigned umn(unsigned a, unsigned b) { return a < b ? a : b; }
__device__ __forceinline__ unsigned umx(unsigned a, unsigned b) { return a < b ? b : a; }

// ---------------- Kernel A: column mean/std(ddof=1) of x ----------------
__global__ __launch_bounds__(1024) void k_colstats_x(const float* __restrict__ x,
                                                     float* __restrict__ mean,
                                                     float* __restrict__ stdx) {
    const int tid = threadIdx.x;
    double s[DD], s2[DD];
#pragma unroll
    for (int c = 0; c < DD; c++) { s[c] = 0.0; s2[c] = 0.0; }
    for (int r = tid; r < NN; r += 1024) {
        const f4* xr = (const f4*)(x + (size_t)r * DD);
#pragma unroll
        for (int q = 0; q < 4; q++) {
            f4 v = xr[q];
            double a;
            a = v.x; s[4*q+0] += a; s2[4*q+0] += a * a;
            a = v.y; s[4*q+1] += a; s2[4*q+1] += a * a;
            a = v.z; s[4*q+2] += a; s2[4*q+2] += a * a;
            a = v.w; s[4*q+3] += a; s2[4*q+3] += a * a;
        }
    }
#pragma unroll
    for (int c = 0; c < DD; c++) {
#pragma unroll
        for (int off = 1; off < 64; off <<= 1) {
            s[c] += __shfl_xor(s[c], off);
            s2[c] += __shfl_xor(s2[c], off);
        }
    }
    __shared__ double red[16][2 * DD];
    const int wid = tid >> 6, lane = tid & 63;
    if (lane == 0) {
#pragma unroll
        for (int c = 0; c < DD; c++) { red[wid][c] = s[c]; red[wid][DD + c] = s2[c]; }
    }
    __syncthreads();
    if (tid < 2 * DD) {
        double t = 0.0;
        for (int w = 0; w < 16; w++) t += red[w][tid];
        red[0][tid] = t;
    }
    __syncthreads();
    if (tid < DD) {
        double sm = red[0][tid], sq = red[0][DD + tid];
        double mu = sm / (double)NN;
        double var = (sq - sm * sm / (double)NN) / (double)(NN - 1);
        mean[tid] = (float)mu;
        stdx[tid] = (float)sqrt(var > 0.0 ? var : 0.0);
    }
}

// ---------------- Kernel B: xc=x-mean (f32), packed fp16 rows, sq of ROUNDED pts ----------------
__global__ __launch_bounds__(256) void k_center(const float* __restrict__ x,
                                                const float* __restrict__ meanp,
                                                float* __restrict__ xc,
                                                uint32_t* __restrict__ xch,
                                                float* __restrict__ sqh) {
    const int i = blockIdx.x * 256 + threadIdx.x;
    const f4* mr = (const f4*)meanp;
    const f4* xr = (const f4*)(x + (size_t)i * DD);
    f4* xo = (f4*)(xc + (size_t)i * DD);
    uint32_t* xh = xch + (size_t)i * 8;
    float s = 0.f;
#pragma unroll
    for (int q = 0; q < 4; q++) {
        f4 m = mr[q];
        f4 v = xr[q];
        v.x -= m.x; v.y -= m.y; v.z -= m.z; v.w -= m.w;
        xo[q] = v;
        _Float16 h0 = (_Float16)v.x, h1 = (_Float16)v.y, h2 = (_Float16)v.z, h3 = (_Float16)v.w;
        float r0 = (float)h0, r1 = (float)h1, r2 = (float)h2, r3 = (float)h3;
        s += r0 * r0 + r1 * r1 + r2 * r2 + r3 * r3;
        h2v p0 = {h0, h1}, p1 = {h2, h3};
        xh[q * 2 + 0] = __builtin_bit_cast(uint32_t, p0);
        xh[q * 2 + 1] = __builtin_bit_cast(uint32_t, p1);
    }
    sqh[i] = s;
}

// ---------------- Kernel C: density (row std of dists) + exact top-15 d2 (SGPR list) ----------------
__global__ __launch_bounds__(512) void k_pass1(const uint32_t* __restrict__ xch,
                                               const float* __restrict__ sqh,
                                               float* __restrict__ density,
                                               float* __restrict__ small15) {
    __shared__ uint32_t tile[8][TJ];   // channel-pair-major: bank = j mod 32 -> 2-way only
    __shared__ float sqs[TJ];
    const int tid = threadIdx.x;
    const int wid = tid >> 6, lane = tid & 63;
    const int i = blockIdx.x * RPB + wid;

    uint32_t xi[8];
    {
        const uint32_t* xip = xch + (size_t)i * 8;
#pragma unroll
        for (int c = 0; c < 8; c++) xi[c] = xip[c];
    }
    const float sqi = sqh[i];

    float s1 = 0.f, s2 = 0.f;
    unsigned lst[KCAP];            // wave-shared (uniform) ascending top-15 of d2 bits
#pragma unroll
    for (int c = 0; c < KCAP; c++) lst[c] = 0x7F7FFFFFu;
    unsigned T = 0x7F7FFFFFu;

    for (int tb = 0; tb < NN; tb += TJ) {
        {
            const uint4* src = (const uint4*)(xch + (size_t)(tb + tid) * 8);
            uint4 a = src[0], b = src[1];
            tile[0][tid] = a.x; tile[1][tid] = a.y; tile[2][tid] = a.z; tile[3][tid] = a.w;
            tile[4][tid] = b.x; tile[5][tid] = b.y; tile[6][tid] = b.z; tile[7][tid] = b.w;
            sqs[tid] = sqh[tb + tid];
        }
        __syncthreads();
#pragma unroll
        for (int r = 0; r < TJ / 64; r++) {
            const int jl = lane + 64 * r;
            float dot = 0.f;
#pragma unroll
            for (int c = 0; c < 8; c++) dot = fdot2a(xi[c], tile[c][jl], dot);
            float d2 = sqs[jl] + sqi - 2.0f * dot;
            d2 = fmaxf(d2, 0.0f);
            float d = sqrtf(d2);
            s1 += d;
            s2 = fmaf(d, d, s2);
            // wave-shared exact top-15 insert (SALU-side, rare after warmup)
            unsigned u = __float_as_uint(d2);
            unsigned long long m = __ballot(u < T);
            while (m) {
                int ln = (int)(__ffsll(m) - 1);
                unsigned v = (unsigned)__builtin_amdgcn_readlane((int)u, ln);
#pragma unroll
                for (int c = 0; c < KCAP; c++) {
                    unsigned lo = umn(lst[c], v);
                    unsigned hi = umx(lst[c], v);
                    lst[c] = lo;
                    v = hi;
                }
                T = lst[KCAP - 1];
                m &= m - 1;
                m &= __ballot(u < T);
            }
        }
        __syncthreads();
    }
    // density (row std, ddof=1); widen to f64 for the final reduce only
    double g1 = s1, g2 = s2;
#pragma unroll
    for (int off = 1; off < 64; off <<= 1) {
        g1 += __shfl_xor(g1, off);
        g2 += __shfl_xor(g2, off);
    }
    if (lane == 0) {
        double var = (g2 - g1 * g1 / (double)NN) / (double)(NN - 1);
        density[i] = (float)sqrt(var > 0.0 ? var : 0.0);
#pragma unroll
        for (int c = 0; c < KCAP; c++)
            small15[(size_t)i * KCAP + c] = __uint_as_float(lst[c]);
    }
}

// ---------------- Kernel D: global adaptive k ----------------
__global__ __launch_bounds__(1024) void k_adaptk(const float* __restrict__ density,
                                                 int* __restrict__ kout) {
    const int tid = threadIdx.x;
    __shared__ float redf[16];
    __shared__ int redi[16];
    __shared__ float dmax_sh;
    const int wid = tid >> 6, lane = tid & 63;
    float mx = 0.f;
    for (int r = tid; r < NN; r += 1024) mx = fmaxf(mx, density[r]);
#pragma unroll
    for (int off = 1; off < 64; off <<= 1) mx = fmaxf(mx, __shfl_xor(mx, off));
    if (lane == 0) redf[wid] = mx;
    __syncthreads();
    if (tid == 0) {
        float m = redf[0];
        for (int w = 1; w < 16; w++) m = fmaxf(m, redf[w]);
        dmax_sh = m;
    }
    __syncthreads();
    const float dmax = dmax_sh + EPSF;
    int ks = 0;
    for (int r = tid; r < NN; r += 1024) {
        float f = density[r] / dmax;
        float kf = fminf(fmaxf(5.0f + 10.0f * f, 5.0f), 20.0f);
        ks += (int)kf;
    }
#pragma unroll
    for (int off = 1; off < 64; off <<= 1) ks += __shfl_xor(ks, off);
    if (lane == 0) redi[wid] = ks;
    __syncthreads();
    if (tid == 0) {
        int t = 0;
        for (int w = 0; w < 16; w++) t += redi[w];
        float meank = (float)t / (float)NN;
        kout[0] = (int)meank;
    }
}

// ---------------- Kernel E: sigma^2 -> kernel weights -> drift ----------------
__global__ __launch_bounds__(512) void k_drift(const uint32_t* __restrict__ xch,
                                               const float* __restrict__ sqh,
                                               const float* __restrict__ small15,
                                               const int* __restrict__ kptr,
                                               float* __restrict__ drift) {
    __shared__ uint32_t tile[8][TJ];
    __shared__ float sqs[TJ];
    const int tid = threadIdx.x;
    const int wid = tid >> 6, lane = tid & 63;
    const int i = blockIdx.x * RPB + wid;

    const int k = kptr[0];
    const float sig2 = small15[(size_t)i * KCAP + (k - 1)];  // k-th smallest d2 == sigma^2
    const float ninv = -1.0f / (2.0f * sig2 + EPSF);

    uint32_t xi[8];
    {
        const uint32_t* xip = xch + (size_t)i * 8;
#pragma unroll
        for (int c = 0; c < 8; c++) xi[c] = xip[c];
    }
    const float sqi = sqh[i];

    float wsum = 0.f;
    __half2 acc[8];
#pragma unroll
    for (int c = 0; c < 8; c++) acc[c] = __float2half2_rn(0.0f);

    for (int tb = 0; tb < NN; tb += TJ) {
        {
            const uint4* src = (const uint4*)(xch + (size_t)(tb + tid) * 8);
            uint4 a = src[0], b = src[1];
            tile[0][tid] = a.x; tile[1][tid] = a.y; tile[2][tid] = a.z; tile[3][tid] = a.w;
            tile[4][tid] = b.x; tile[5][tid] = b.y; tile[6][tid] = b.z; tile[7][tid] = b.w;
            sqs[tid] = sqh[tb + tid];
        }
        __syncthreads();
#pragma unroll
        for (int r = 0; r < TJ / 64; r++) {
            const int jl = lane + 64 * r;
            uint32_t xj[8];
#pragma unroll
            for (int c = 0; c < 8; c++) xj[c] = tile[c][jl];
            float dot = 0.f;
#pragma unroll
            for (int c = 0; c < 8; c++) dot = fdot2a(xi[c], xj[c], dot);
            float d2 = sqs[jl] + sqi - 2.0f * dot;
            float d = sqrtf(fmaxf(d2, 0.0f));
            float w = __expf(d * ninv);
            wsum += w;
            __half2 wh = __float2half2_rn(w);
#pragma unroll
            for (int c = 0; c < 8; c++)
                acc[c] = __hfma2(wh, __builtin_bit_cast(__half2, xj[c]), acc[c]);
        }
        __syncthreads();
    }
    float num[16];
#pragma unroll
    for (int c = 0; c < 8; c++) {
        float2 f = __half22float2(acc[c]);
        num[2 * c + 0] = f.x;
        num[2 * c + 1] = f.y;
    }
#pragma unroll
    for (int off = 1; off < 64; off <<= 1) {
        wsum += __shfl_xor(wsum, off);
#pragma unroll
        for (int c = 0; c < 16; c++) num[c] += __shfl_xor(num[c], off);
    }
    if (lane == 0) {
        const float inv = 1.0f / (wsum + EPSF);
        f4* out = (f4*)(drift + (size_t)i * DD);
#pragma unroll
        for (int q = 0; q < 4; q++) {
            f4 o = {num[4*q+0] * inv, num[4*q+1] * inv, num[4*q+2] * inv, num[4*q+3] * inv};
            out[q] = o;
        }
    }
}

// ---------------- Kernel G1: h_pre = xc + step*(drift - xc) + 0.01*noise ----------------
__global__ __launch_bounds__(256) void k_hpre(const float* __restrict__ xc,
                                              const float* __restrict__ drift,
                                              const float* __restrict__ noise,
                                              const float* __restrict__ alpha,
                                              float* __restrict__ hpre) {
    const int i = blockIdx.x * 256 + threadIdx.x;
    const float step = powf(16.0f, -alpha[0]);
    const f4* xr = (const f4*)(xc + (size_t)i * DD);
    const f4* dr = (const f4*)(drift + (size_t)i * DD);
    const f4* nr = (const f4*)(noise + (size_t)i * DD);
    f4* ho = (f4*)(hpre + (size_t)i * DD);
#pragma unroll
    for (int q = 0; q < 4; q++) {
        f4 a = xr[q], b = dr[q], n = nr[q], o;
        o.x = a.x + step * (b.x - a.x) + n.x * 0.01f;
        o.y = a.y + step * (b.y - a.y) + n.y * 0.01f;
        o.z = a.z + step * (b.z - a.z) + n.z * 0.01f;
        o.w = a.w + step * (b.w - a.w) + n.w * 0.01f;
        ho[q] = o;
    }
}

// ---------------- Kernel G2: column std of h_pre -> ratio = stdx/(stdh+eps) ----------------
__global__ __launch_bounds__(1024) void k_colstats_h(const float* __restrict__ h,
                                                     const float* __restrict__ stdx,
                                                     float* __restrict__ ratio) {
    const int tid = threadIdx.x;
    double s[DD], s2[DD];
#pragma unroll
    for (int c = 0; c < DD; c++) { s[c] = 0.0; s2[c] = 0.0; }
    for (int r = tid; r < NN; r += 1024) {
        const f4* xr = (const f4*)(h + (size_t)r * DD);
#pragma unroll
        for (int q = 0; q < 4; q++) {
            f4 v = xr[q];
            double a;
            a = v.x; s[4*q+0] += a; s2[4*q+0] += a * a;
            a = v.y; s[4*q+1] += a; s2[4*q+1] += a * a;
            a = v.z; s[4*q+2] += a; s2[4*q+2] += a * a;
            a = v.w; s[4*q+3] += a; s2[4*q+3] += a * a;
        }
    }
#pragma unroll
    for (int c = 0; c < DD; c++) {
#pragma unroll
        for (int off = 1; off < 64; off <<= 1) {
            s[c] += __shfl_xor(s[c], off);
            s2[c] += __shfl_xor(s2[c], off);
        }
    }
    __shared__ double red[16][2 * DD];
    const int wid = tid >> 6, lane = tid & 63;
    if (lane == 0) {
#pragma unroll
        for (int c = 0; c < DD; c++) { red[wid][c] = s[c]; red[wid][DD + c] = s2[c]; }
    }
    __syncthreads();
    if (tid < 2 * DD) {
        double t = 0.0;
        for (int w = 0; w < 16; w++) t += red[w][tid];
        red[0][tid] = t;
    }
    __syncthreads();
    if (tid < DD) {
        double sm = red[0][tid], sq = red[0][DD + tid];
        double var = (sq - sm * sm / (double)NN) / (double)(NN - 1);
        float stdh = (float)sqrt(var > 0.0 ? var : 0.0);
        ratio[tid] = stdx[tid] / (stdh + EPSF);
    }
}

// ---------------- Kernel G3: out = h_pre * ratio + mean (in place) ----------------
__global__ __launch_bounds__(256) void k_final(float* __restrict__ h,
                                               const float* __restrict__ ratio,
                                               const float* __restrict__ meanp) {
    const int i = blockIdx.x * 256 + threadIdx.x;
    const f4* rr = (const f4*)ratio;
    const f4* mr = (const f4*)meanp;
    f4* hr = (f4*)(h + (size_t)i * DD);
#pragma unroll
    for (int q = 0; q < 4; q++) {
        f4 v = hr[q], rv = rr[q], mv = mr[q];
        v.x = v.x * rv.x + mv.x;
        v.y = v.y * rv.y + mv.y;
        v.z = v.z * rv.z + mv.z;
        v.w = v.w * rv.w + mv.w;
        hr[q] = v;
    }
}

extern "C" void kernel_launch(void* const* d_in, const int* in_sizes, int n_in,
                              void* d_out, int out_size, void* d_ws, size_t ws_size,
                              hipStream_t stream) {
    (void)in_sizes; (void)n_in; (void)out_size; (void)ws_size;
    const float* x = (const float*)d_in[0];
    const float* noise = (const float*)d_in[1];
    const float* alpha = (const float*)d_in[2];
    float* out = (float*)d_out;

    float* ws = (float*)d_ws;
    float*    xc    = ws;                          // N*D f32
    uint32_t* xch   = (uint32_t*)(xc + (size_t)NN * DD);  // N*8 u32 (packed fp16)
    float*    sqh   = (float*)(xch + (size_t)NN * 8);     // N
    float*    den   = sqh + NN;                    // N
    float*    sml   = den + NN;                    // N*KCAP (d2 values, ascending)
    float*    drf   = sml + (size_t)NN * KCAP;     // N*D
    float*    meanp = drf + (size_t)NN * DD;       // 16
    float*    stdx  = meanp + DD;                  // 16
    float*    ratio = stdx + DD;                   // 16
    int*      kptr  = (int*)(ratio + DD);          // 1

    k_colstats_x<<<1, 1024, 0, stream>>>(x, meanp, stdx);
    k_center<<<NN / 256, 256, 0, stream>>>(x, meanp, xc, xch, sqh);
    k_pass1<<<NN / RPB, 512, 0, stream>>>(xch, sqh, den, sml);
    k_adaptk<<<1, 1024, 0, stream>>>(den, kptr);
    k_drift<<<NN / RPB, 512, 0, stream>>>(xch, sqh, sml, kptr, drf);
    k_hpre<<<NN / 256, 256, 0, stream>>>(xc, drf, noise, alpha, out);
    k_colstats_h<<<1, 1024, 0, stream>>>(out, stdx, ratio);
    k_final<<<NN / 256, 256, 0, stream>>>(out, ratio, meanp);
}

// Round 3
// 248.109 us; speedup vs baseline: 1.6617x; 1.1437x over previous
//
#include <hip/hip_runtime.h>
#include <hip/hip_fp16.h>
#include <cfloat>
#include <cmath>
#include <cstdint>

#define NN 8192
#define DD 16
#define KCAP 15      // k = int(mean(clip(5+10f,5,20))), f<=1 -> k in [5,15]
#define EPSF 1e-8f
#define TJ 1024      // j-tile per block
#define RPW 2        // rows per wave

typedef float4 f4;
typedef _Float16 h2v __attribute__((ext_vector_type(2)));

__device__ __forceinline__ float fdot2a(uint32_t a, uint32_t b, float c) {
#if defined(__has_builtin) && __has_builtin(__builtin_amdgcn_fdot2)
    return __builtin_amdgcn_fdot2(__builtin_bit_cast(h2v, a), __builtin_bit_cast(h2v, b), c, false);
#else
    __half2 ah = __builtin_bit_cast(__half2, a), bh = __builtin_bit_cast(__half2, b);
    float2 af = __half22float2(ah), bf = __half22float2(bh);
    return fmaf(af.x, bf.x, fmaf(af.y, bf.y, c));
#endif
}

__device__ __forceinline__ unsigned umn(unsigned a, unsigned b) { return a < b ? a : b; }
__device__ __forceinline__ unsigned umx(unsigned a, unsigned b) { return a < b ? b : a; }

__device__ __forceinline__ float dot8(const uint32_t xa[8], const uint32_t xb[8]) {
    float d = 0.f;
#pragma unroll
    for (int c = 0; c < 8; c++) d = fdot2a(xa[c], xb[c], d);
    return d;
}

// exact wave-shared top-KCAP insert; values uniform (readlane) -> SALU network
__device__ __forceinline__ void topk_insert(unsigned (&lst)[KCAP], unsigned& T, unsigned u) {
    unsigned long long m = __ballot(u < T);
    while (m) {
        int ln = (int)(__ffsll(m) - 1);
        unsigned v = (unsigned)__builtin_amdgcn_readlane((int)u, ln);
#pragma unroll
        for (int c = 0; c < KCAP; c++) {
            unsigned lo = umn(lst[c], v);
            unsigned hi = umx(lst[c], v);
            lst[c] = lo;
            v = hi;
        }
        T = lst[KCAP - 1];
        m &= m - 1;
        m &= __ballot(u < T);
    }
}

// ---------------- column-stat partials (sum, sumsq) of a [N][16] f32 array ----------------
__device__ __forceinline__ void colstat_reduce_store(const float h[DD], double* __restrict__ part,
                                                     int blk, int tid) {
    const int lane = tid & 63, wid = tid >> 6;
    double s[DD], s2[DD];
#pragma unroll
    for (int c = 0; c < DD; c++) { double a = (double)h[c]; s[c] = a; s2[c] = a * a; }
#pragma unroll
    for (int c = 0; c < DD; c++) {
#pragma unroll
        for (int off = 1; off < 64; off <<= 1) {
            s[c] += __shfl_xor(s[c], off);
            s2[c] += __shfl_xor(s2[c], off);
        }
    }
    __shared__ double red[4][2 * DD];
    if (lane == 0) {
#pragma unroll
        for (int c = 0; c < DD; c++) { red[wid][c] = s[c]; red[wid][DD + c] = s2[c]; }
    }
    __syncthreads();
    if (tid < 2 * DD) {
        double t = red[0][tid] + red[1][tid] + red[2][tid] + red[3][tid];
        part[(size_t)blk * 2 * DD + tid] = t;
    }
}

__global__ __launch_bounds__(256) void k_stats_part_x(const float* __restrict__ x,
                                                      double* __restrict__ part) {
    const int i = blockIdx.x * 256 + threadIdx.x;
    float h[DD];
    const f4* xr = (const f4*)(x + (size_t)i * DD);
#pragma unroll
    for (int q = 0; q < 4; q++) {
        f4 v = xr[q];
        h[4*q+0] = v.x; h[4*q+1] = v.y; h[4*q+2] = v.z; h[4*q+3] = v.w;
    }
    colstat_reduce_store(h, part, blockIdx.x, threadIdx.x);
}

__global__ __launch_bounds__(64) void k_stats_fin1(const double* __restrict__ part,
                                                   float* __restrict__ mean,
                                                   float* __restrict__ stdx) {
    const int c = threadIdx.x;
    if (c < DD) {
        double s = 0.0, q = 0.0;
        for (int b = 0; b < 32; b++) {
            s += part[(size_t)b * 2 * DD + c];
            q += part[(size_t)b * 2 * DD + DD + c];
        }
        double mu = s / (double)NN;
        double var = (q - s * s / (double)NN) / (double)(NN - 1);
        mean[c] = (float)mu;
        stdx[c] = (float)sqrt(var > 0.0 ? var : 0.0);
    }
}

// ---------------- center: xc=x-mean (f32), packed fp16 rows, sq of ROUNDED pts ----------------
__global__ __launch_bounds__(256) void k_center(const float* __restrict__ x,
                                                const float* __restrict__ meanp,
                                                float* __restrict__ xc,
                                                uint32_t* __restrict__ xch,
                                                float* __restrict__ sqh) {
    const int i = blockIdx.x * 256 + threadIdx.x;
    const f4* mr = (const f4*)meanp;
    const f4* xr = (const f4*)(x + (size_t)i * DD);
    f4* xo = (f4*)(xc + (size_t)i * DD);
    uint32_t* xh = xch + (size_t)i * 8;
    float s = 0.f;
#pragma unroll
    for (int q = 0; q < 4; q++) {
        f4 m = mr[q];
        f4 v = xr[q];
        v.x -= m.x; v.y -= m.y; v.z -= m.z; v.w -= m.w;
        xo[q] = v;
        _Float16 h0 = (_Float16)v.x, h1 = (_Float16)v.y, h2 = (_Float16)v.z, h3 = (_Float16)v.w;
        float r0 = (float)h0, r1 = (float)h1, r2 = (float)h2, r3 = (float)h3;
        s += r0 * r0 + r1 * r1 + r2 * r2 + r3 * r3;
        h2v p0 = {h0, h1}, p1 = {h2, h3};
        xh[q * 2 + 0] = __builtin_bit_cast(uint32_t, p0);
        xh[q * 2 + 1] = __builtin_bit_cast(uint32_t, p1);
    }
    sqh[i] = s;
}

// ---------------- pass1: density (row std of dists) + exact top-15 d2 ----------------
__global__ __launch_bounds__(512, 4) void k_pass1(const uint32_t* __restrict__ xch,
                                                  const float* __restrict__ sqh,
                                                  float* __restrict__ density,
                                                  float* __restrict__ small15) {
    __shared__ __align__(16) uint32_t tile[8][TJ];   // 32 KB, chanpair-major
    __shared__ __align__(16) float sqs[TJ];          // 4 KB
    const int tid = threadIdx.x;
    const int wid = tid >> 6, lane = tid & 63;
    const int i0 = blockIdx.x * (8 * RPW) + wid * RPW;
    const int i1 = i0 + 1;

    uint32_t xi0[8], xi1[8];
    {
        const uint32_t* p0 = xch + (size_t)i0 * 8;
        const uint32_t* p1 = xch + (size_t)i1 * 8;
#pragma unroll
        for (int c = 0; c < 8; c++) { xi0[c] = p0[c]; xi1[c] = p1[c]; }
    }
    const float sqi0 = sqh[i0], sqi1 = sqh[i1];

    float s1a = 0.f, s2a = 0.f, s1b = 0.f, s2b = 0.f;
    unsigned lstA[KCAP], lstB[KCAP];
#pragma unroll
    for (int c = 0; c < KCAP; c++) { lstA[c] = 0x7F7FFFFFu; lstB[c] = 0x7F7FFFFFu; }
    unsigned TA = 0x7F7FFFFFu, TB = 0x7F7FFFFFu;

    for (int tb = 0; tb < NN; tb += TJ) {
        for (int t = tid; t < TJ; t += 512) {
            const uint4* src = (const uint4*)(xch + (size_t)(tb + t) * 8);
            uint4 a = src[0], b = src[1];
            tile[0][t] = a.x; tile[1][t] = a.y; tile[2][t] = a.z; tile[3][t] = a.w;
            tile[4][t] = b.x; tile[5][t] = b.y; tile[6][t] = b.z; tile[7][t] = b.w;
            sqs[t] = sqh[tb + t];
        }
        __syncthreads();
#pragma unroll 1
        for (int q = 0; q < TJ / 256; q++) {
            const int jb = (q << 8) + (lane << 2);
            uint32_t xj[4][8];
#pragma unroll
            for (int c = 0; c < 8; c++) {
                uint4 w = *(const uint4*)&tile[c][jb];
                xj[0][c] = w.x; xj[1][c] = w.y; xj[2][c] = w.z; xj[3][c] = w.w;
            }
            float4 s4 = *(const float4*)&sqs[jb];
            float sqj[4] = {s4.x, s4.y, s4.z, s4.w};
#pragma unroll
            for (int t = 0; t < 4; t++) {
                float dot0 = dot8(xi0, xj[t]);
                float d20 = fmaxf(fmaf(-2.f, dot0, sqj[t] + sqi0), 0.f);
                float d0 = sqrtf(d20);
                s1a += d0;
                s2a = fmaf(d0, d0, s2a);
                topk_insert(lstA, TA, __float_as_uint(d20));
                float dot1 = dot8(xi1, xj[t]);
                float d21 = fmaxf(fmaf(-2.f, dot1, sqj[t] + sqi1), 0.f);
                float d1 = sqrtf(d21);
                s1b += d1;
                s2b = fmaf(d1, d1, s2b);
                topk_insert(lstB, TB, __float_as_uint(d21));
            }
        }
        __syncthreads();
    }
    double g1a = s1a, g2a = s2a, g1b = s1b, g2b = s2b;
#pragma unroll
    for (int off = 1; off < 64; off <<= 1) {
        g1a += __shfl_xor(g1a, off); g2a += __shfl_xor(g2a, off);
        g1b += __shfl_xor(g1b, off); g2b += __shfl_xor(g2b, off);
    }
    if (lane == 0) {
        double va = (g2a - g1a * g1a / (double)NN) / (double)(NN - 1);
        double vb = (g2b - g1b * g1b / (double)NN) / (double)(NN - 1);
        density[i0] = (float)sqrt(va > 0.0 ? va : 0.0);
        density[i1] = (float)sqrt(vb > 0.0 ? vb : 0.0);
#pragma unroll
        for (int c = 0; c < KCAP; c++) {
            small15[(size_t)i0 * KCAP + c] = __uint_as_float(lstA[c]);
            small15[(size_t)i1 * KCAP + c] = __uint_as_float(lstB[c]);
        }
    }
}

// ---------------- global adaptive k ----------------
__global__ __launch_bounds__(1024) void k_adaptk(const float* __restrict__ density,
                                                 int* __restrict__ kout) {
    const int tid = threadIdx.x;
    __shared__ float redf[16];
    __shared__ int redi[16];
    __shared__ float dmax_sh;
    const int wid = tid >> 6, lane = tid & 63;
    float mx = 0.f;
    for (int r = tid; r < NN; r += 1024) mx = fmaxf(mx, density[r]);
#pragma unroll
    for (int off = 1; off < 64; off <<= 1) mx = fmaxf(mx, __shfl_xor(mx, off));
    if (lane == 0) redf[wid] = mx;
    __syncthreads();
    if (tid == 0) {
        float m = redf[0];
        for (int w = 1; w < 16; w++) m = fmaxf(m, redf[w]);
        dmax_sh = m;
    }
    __syncthreads();
    const float dmax = dmax_sh + EPSF;
    int ks = 0;
    for (int r = tid; r < NN; r += 1024) {
        float f = density[r] / dmax;
        float kf = fminf(fmaxf(5.0f + 10.0f * f, 5.0f), 20.0f);
        ks += (int)kf;
    }
#pragma unroll
    for (int off = 1; off < 64; off <<= 1) ks += __shfl_xor(ks, off);
    if (lane == 0) redi[wid] = ks;
    __syncthreads();
    if (tid == 0) {
        int t = 0;
        for (int w = 0; w < 16; w++) t += redi[w];
        float meank = (float)t / (float)NN;
        kout[0] = (int)meank;
    }
}

// ---------------- drift: sigma^2 -> kernel weights -> drift ----------------
__global__ __launch_bounds__(512, 4) void k_drift(const uint32_t* __restrict__ xch,
                                                  const float* __restrict__ sqh,
                                                  const float* __restrict__ small15,
                                                  const int* __restrict__ kptr,
                                                  float* __restrict__ drift) {
    __shared__ __align__(16) uint32_t tile[8][TJ];
    __shared__ __align__(16) float sqs[TJ];
    const int tid = threadIdx.x;
    const int wid = tid >> 6, lane = tid & 63;
    const int i0 = blockIdx.x * (8 * RPW) + wid * RPW;
    const int i1 = i0 + 1;

    const int k = kptr[0];
    const float ninv0 = -1.0f / (2.0f * small15[(size_t)i0 * KCAP + (k - 1)] + EPSF);
    const float ninv1 = -1.0f / (2.0f * small15[(size_t)i1 * KCAP + (k - 1)] + EPSF);

    uint32_t xi0[8], xi1[8];
    {
        const uint32_t* p0 = xch + (size_t)i0 * 8;
        const uint32_t* p1 = xch + (size_t)i1 * 8;
#pragma unroll
        for (int c = 0; c < 8; c++) { xi0[c] = p0[c]; xi1[c] = p1[c]; }
    }
    const float sqi0 = sqh[i0], sqi1 = sqh[i1];

    float wsA = 0.f, wsB = 0.f;
    __half2 accA[8], accB[8];
#pragma unroll
    for (int c = 0; c < 8; c++) { accA[c] = __float2half2_rn(0.f); accB[c] = __float2half2_rn(0.f); }

    for (int tb = 0; tb < NN; tb += TJ) {
        for (int t = tid; t < TJ; t += 512) {
            const uint4* src = (const uint4*)(xch + (size_t)(tb + t) * 8);
            uint4 a = src[0], b = src[1];
            tile[0][t] = a.x; tile[1][t] = a.y; tile[2][t] = a.z; tile[3][t] = a.w;
            tile[4][t] = b.x; tile[5][t] = b.y; tile[6][t] = b.z; tile[7][t] = b.w;
            sqs[t] = sqh[tb + t];
        }
        __syncthreads();
#pragma unroll 1
        for (int q = 0; q < TJ / 256; q++) {
            const int jb = (q << 8) + (lane << 2);
            uint32_t xj[4][8];
#pragma unroll
            for (int c = 0; c < 8; c++) {
                uint4 w = *(const uint4*)&tile[c][jb];
                xj[0][c] = w.x; xj[1][c] = w.y; xj[2][c] = w.z; xj[3][c] = w.w;
            }
            float4 s4 = *(const float4*)&sqs[jb];
            float sqj[4] = {s4.x, s4.y, s4.z, s4.w};
#pragma unroll
            for (int t = 0; t < 4; t++) {
                float dot0 = dot8(xi0, xj[t]);
                float d20 = fmaf(-2.f, dot0, sqj[t] + sqi0);
                float d0 = sqrtf(fmaxf(d20, 0.f));
                float w0 = __expf(d0 * ninv0);
                wsA += w0;
                __half2 wh0 = __float2half2_rn(w0);
                float dot1 = dot8(xi1, xj[t]);
                float d21 = fmaf(-2.f, dot1, sqj[t] + sqi1);
                float d1 = sqrtf(fmaxf(d21, 0.f));
                float w1 = __expf(d1 * ninv1);
                wsB += w1;
                __half2 wh1 = __float2half2_rn(w1);
#pragma unroll
                for (int c = 0; c < 8; c++) {
                    accA[c] = __hfma2(wh0, __builtin_bit_cast(__half2, xj[t][c]), accA[c]);
                    accB[c] = __hfma2(wh1, __builtin_bit_cast(__half2, xj[t][c]), accB[c]);
                }
            }
        }
        __syncthreads();
    }
    float fA[16], fB[16];
#pragma unroll
    for (int c = 0; c < 8; c++) {
        float2 ua = __half22float2(accA[c]);
        float2 ub = __half22float2(accB[c]);
        fA[2*c] = ua.x; fA[2*c+1] = ua.y;
        fB[2*c] = ub.x; fB[2*c+1] = ub.y;
    }
#pragma unroll
    for (int off = 1; off < 64; off <<= 1) {
        wsA += __shfl_xor(wsA, off);
        wsB += __shfl_xor(wsB, off);
#pragma unroll
        for (int c = 0; c < 16; c++) {
            fA[c] += __shfl_xor(fA[c], off);
            fB[c] += __shfl_xor(fB[c], off);
        }
    }
    if (lane == 0) {
        const float ia = 1.0f / (wsA + EPSF);
        const float ib = 1.0f / (wsB + EPSF);
        f4* o0 = (f4*)(drift + (size_t)i0 * DD);
        f4* o1 = (f4*)(drift + (size_t)i1 * DD);
#pragma unroll
        for (int q = 0; q < 4; q++) {
            f4 a = {fA[4*q] * ia, fA[4*q+1] * ia, fA[4*q+2] * ia, fA[4*q+3] * ia};
            f4 b = {fB[4*q] * ib, fB[4*q+1] * ib, fB[4*q+2] * ib, fB[4*q+3] * ib};
            o0[q] = a;
            o1[q] = b;
        }
    }
}

// ---------------- fused: h = xc + step*(drift-xc) + 0.01*noise; write h; col-stat partials ----------------
__global__ __launch_bounds__(256) void k_hpre_stats(const float* __restrict__ xc,
                                                    const float* __restrict__ drift,
                                                    const float* __restrict__ noise,
                                                    const float* __restrict__ alpha,
                                                    float* __restrict__ hpre,
                                                    double* __restrict__ part) {
    const int i = blockIdx.x * 256 + threadIdx.x;
    const float step = powf(16.0f, -alpha[0]);
    const f4* xr = (const f4*)(xc + (size_t)i * DD);
    const f4* dr = (const f4*)(drift + (size_t)i * DD);
    const f4* nr = (const f4*)(noise + (size_t)i * DD);
    f4* ho = (f4*)(hpre + (size_t)i * DD);
    float h[DD];
#pragma unroll
    for (int q = 0; q < 4; q++) {
        f4 a = xr[q], b = dr[q], n = nr[q], o;
        o.x = a.x + step * (b.x - a.x) + n.x * 0.01f;
        o.y = a.y + step * (b.y - a.y) + n.y * 0.01f;
        o.z = a.z + step * (b.z - a.z) + n.z * 0.01f;
        o.w = a.w + step * (b.w - a.w) + n.w * 0.01f;
        ho[q] = o;
        h[4*q+0] = o.x; h[4*q+1] = o.y; h[4*q+2] = o.z; h[4*q+3] = o.w;
    }
    colstat_reduce_store(h, part, blockIdx.x, threadIdx.x);
}

__global__ __launch_bounds__(64) void k_stats_fin2(const double* __restrict__ part,
                                                   const float* __restrict__ stdx,
                                                   float* __restrict__ ratio) {
    const int c = threadIdx.x;
    if (c < DD) {
        double s = 0.0, q = 0.0;
        for (int b = 0; b < 32; b++) {
            s += part[(size_t)b * 2 * DD + c];
            q += part[(size_t)b * 2 * DD + DD + c];
        }
        double var = (q - s * s / (double)NN) / (double)(NN - 1);
        float stdh = (float)sqrt(var > 0.0 ? var : 0.0);
        ratio[c] = stdx[c] / (stdh + EPSF);
    }
}

// ---------------- final: out = h * ratio + mean (in place) ----------------
__global__ __launch_bounds__(256) void k_final(float* __restrict__ h,
                                               const float* __restrict__ ratio,
                                               const float* __restrict__ meanp) {
    const int i = blockIdx.x * 256 + threadIdx.x;
    const f4* rr = (const f4*)ratio;
    const f4* mr = (const f4*)meanp;
    f4* hr = (f4*)(h + (size_t)i * DD);
#pragma unroll
    for (int q = 0; q < 4; q++) {
        f4 v = hr[q], rv = rr[q], mv = mr[q];
        v.x = v.x * rv.x + mv.x;
        v.y = v.y * rv.y + mv.y;
        v.z = v.z * rv.z + mv.z;
        v.w = v.w * rv.w + mv.w;
        hr[q] = v;
    }
}

extern "C" void kernel_launch(void* const* d_in, const int* in_sizes, int n_in,
                              void* d_out, int out_size, void* d_ws, size_t ws_size,
                              hipStream_t stream) {
    (void)in_sizes; (void)n_in; (void)out_size; (void)ws_size;
    const float* x = (const float*)d_in[0];
    const float* noise = (const float*)d_in[1];
    const float* alpha = (const float*)d_in[2];
    float* out = (float*)d_out;

    double* part1 = (double*)d_ws;                 // 32 blocks * 32
    double* part2 = part1 + 32 * 32;               // 32 blocks * 32
    float*    xc    = (float*)(part2 + 32 * 32);   // N*D f32
    uint32_t* xch   = (uint32_t*)(xc + (size_t)NN * DD);  // N*8 (packed fp16)
    float*    sqh   = (float*)(xch + (size_t)NN * 8);     // N
    float*    den   = sqh + NN;                    // N
    float*    sml   = den + NN;                    // N*KCAP
    float*    drf   = sml + (size_t)NN * KCAP;     // N*D
    float*    meanp = drf + (size_t)NN * DD;       // 16
    float*    stdx  = meanp + DD;                  // 16
    float*    ratio = stdx + DD;                   // 16
    int*      kptr  = (int*)(ratio + DD);          // 1

    k_stats_part_x<<<32, 256, 0, stream>>>(x, part1);
    k_stats_fin1<<<1, 64, 0, stream>>>(part1, meanp, stdx);
    k_center<<<32, 256, 0, stream>>>(x, meanp, xc, xch, sqh);
    k_pass1<<<NN / (8 * RPW), 512, 0, stream>>>(xch, sqh, den, sml);
    k_adaptk<<<1, 1024, 0, stream>>>(den, kptr);
    k_drift<<<NN / (8 * RPW), 512, 0, stream>>>(xch, sqh, sml, kptr, drf);
    k_hpre_stats<<<32, 256, 0, stream>>>(xc, drf, noise, alpha, out, part2);
    k_stats_fin2<<<1, 64, 0, stream>>>(part2, stdx, ratio);
    k_final<<<32, 256, 0, stream>>>(out, ratio, meanp);
}

// Round 5
// 208.466 us; speedup vs baseline: 1.9776x; 1.1902x over previous
//
#include <hip/hip_runtime.h>
#include <hip/hip_fp16.h>
#include <cfloat>
#include <cmath>
#include <cstdint>

#define NN 8192
#define DD 16
#define EPSF 1e-8f
#define CH 8            // j-chunks
#define CHJ 1024        // j per chunk

typedef float4 f4;
typedef _Float16 f16x4 __attribute__((ext_vector_type(4)));
typedef _Float16 f16x2 __attribute__((ext_vector_type(2)));
typedef float f32x4 __attribute__((ext_vector_type(4)));

__device__ __forceinline__ unsigned umn(unsigned a, unsigned b) { return a < b ? a : b; }
__device__ __forceinline__ unsigned umx(unsigned a, unsigned b) { return a < b ? b : a; }

// pack two f32 -> one dword of 2 x f16 (RTZ)
__device__ __forceinline__ uint32_t pkrtz(float a, float b) {
    return __builtin_bit_cast(uint32_t, __builtin_amdgcn_cvt_pkrtz(a, b));
}

// ---------------- column-stat partials ----------------
__device__ __forceinline__ void colstat_reduce_store(const float h[DD], double* __restrict__ part,
                                                     int blk, int tid) {
    const int lane = tid & 63, wid = tid >> 6;
    double s[DD], s2[DD];
#pragma unroll
    for (int c = 0; c < DD; c++) { double a = (double)h[c]; s[c] = a; s2[c] = a * a; }
#pragma unroll
    for (int c = 0; c < DD; c++) {
#pragma unroll
        for (int off = 1; off < 64; off <<= 1) {
            s[c] += __shfl_xor(s[c], off);
            s2[c] += __shfl_xor(s2[c], off);
        }
    }
    __shared__ double red[4][2 * DD];
    if (lane == 0) {
#pragma unroll
        for (int c = 0; c < DD; c++) { red[wid][c] = s[c]; red[wid][DD + c] = s2[c]; }
    }
    __syncthreads();
    if (tid < 2 * DD) {
        double t = red[0][tid] + red[1][tid] + red[2][tid] + red[3][tid];
        part[(size_t)blk * 2 * DD + tid] = t;
    }
}

__global__ __launch_bounds__(256) void k_stats_part_x(const float* __restrict__ x,
                                                      double* __restrict__ part) {
    const int i = blockIdx.x * 256 + threadIdx.x;
    float h[DD];
    const f4* xr = (const f4*)(x + (size_t)i * DD);
#pragma unroll
    for (int q = 0; q < 4; q++) {
        f4 v = xr[q];
        h[4*q+0] = v.x; h[4*q+1] = v.y; h[4*q+2] = v.z; h[4*q+3] = v.w;
    }
    colstat_reduce_store(h, part, blockIdx.x, threadIdx.x);
}

__global__ __launch_bounds__(64) void k_stats_fin1(const double* __restrict__ part,
                                                   float* __restrict__ mean,
                                                   float* __restrict__ stdx) {
    const int c = threadIdx.x;
    if (c < DD) {
        double s = 0.0, q = 0.0;
        for (int b = 0; b < 32; b++) {
            s += part[(size_t)b * 2 * DD + c];
            q += part[(size_t)b * 2 * DD + DD + c];
        }
        double mu = s / (double)NN;
        double var = (q - s * s / (double)NN) / (double)(NN - 1);
        mean[c] = (float)mu;
        stdx[c] = (float)sqrt(var > 0.0 ? var : 0.0);
    }
}

// ---------------- center: xc=x-mean (f32), packed fp16 rows, sq of ROUNDED pts ----------------
__global__ __launch_bounds__(256) void k_center(const float* __restrict__ x,
                                                const float* __restrict__ meanp,
                                                float* __restrict__ xc,
                                                uint32_t* __restrict__ xch,
                                                float* __restrict__ sqh) {
    const int i = blockIdx.x * 256 + threadIdx.x;
    const f4* mr = (const f4*)meanp;
    const f4* xr = (const f4*)(x + (size_t)i * DD);
    f4* xo = (f4*)(xc + (size_t)i * DD);
    uint32_t* xh = xch + (size_t)i * 8;
    float s = 0.f;
#pragma unroll
    for (int q = 0; q < 4; q++) {
        f4 m = mr[q];
        f4 v = xr[q];
        v.x -= m.x; v.y -= m.y; v.z -= m.z; v.w -= m.w;
        xo[q] = v;
        _Float16 h0 = (_Float16)v.x, h1 = (_Float16)v.y, h2 = (_Float16)v.z, h3 = (_Float16)v.w;
        float r0 = (float)h0, r1 = (float)h1, r2 = (float)h2, r3 = (float)h3;
        s += r0 * r0 + r1 * r1 + r2 * r2 + r3 * r3;
        f16x2 p0 = {h0, h1}, p1 = {h2, h3};
        xh[q * 2 + 0] = __builtin_bit_cast(uint32_t, p0);
        xh[q * 2 + 1] = __builtin_bit_cast(uint32_t, p1);
    }
    sqh[i] = s;
}

// ---------------- pass1 (MFMA): s1/s2 partials + exact per-chunk top-15 d2 ----------------
// Each block: 8 waves = 8 i-tiles of 16 rows; one j-chunk of 1024 shared via LDS.
// MFMA orientation: A = Xj tile (m=j), B = Xi rows (n=i) -> D[m=j][n=i];
// lane: i = lane&15, j = jt*16 + (lane>>4)*4 + q.
__global__ __launch_bounds__(512, 2) void k_pass1_mfma(const uint32_t* __restrict__ xch,
                                                       const float* __restrict__ sqh,
                                                       float* __restrict__ s1p,
                                                       float* __restrict__ s2p,
                                                       float* __restrict__ smlp) {
    __shared__ uint32_t tileA[8 * CHJ];   // frag-order, 32KB (aliased as lw after loop)
    __shared__ float sqs[CHJ];            // 4KB
    const int tid = threadIdx.x, wid = tid >> 6, lane = tid & 63;
    const int r = lane & 15, h = lane >> 4;
    const int iG = blockIdx.x >> 3, chunk = blockIdx.x & 7;
    const int jbase = chunk << 10;
    const int i0 = (iG * 8 + wid) << 4;
    const int i = i0 + r;

    // B-frag: Xi[i=lane&15][k=4h+b] = xch row i, dwords {2h, 2h+1}
    uint2 bu = *(const uint2*)(xch + (size_t)i * 8 + h * 2);
    f16x4 bf = __builtin_bit_cast(f16x4, bu);
    const float sqi = sqh[i];

    // stage chunk into frag-order tile
#pragma unroll
    for (int s = 0; s < 2; s++) {
        int jl = tid + s * 512;
        const uint4* src = (const uint4*)(xch + (size_t)(jbase + jl) * 8);
        uint4 a = src[0], b = src[1];
        uint32_t* base = tileA + ((jl >> 4) * 128 + (jl & 15) * 2);
        *(uint2*)(base)      = make_uint2(a.x, a.y);
        *(uint2*)(base + 32) = make_uint2(a.z, a.w);
        *(uint2*)(base + 64) = make_uint2(b.x, b.y);
        *(uint2*)(base + 96) = make_uint2(b.z, b.w);
        sqs[jl] = sqh[jbase + jl];
    }
    __syncthreads();

    float s1 = 0.f, s2 = 0.f;
    unsigned lst[15];
#pragma unroll
    for (int c = 0; c < 15; c++) lst[c] = 0x7F7FFFFFu;
    unsigned T = 0x7F7FFFFFu, Tg = 0x7F7FFFFFu;

    for (int jt = 0; jt < CHJ / 16; jt++) {
        uint2 au = *(const uint2*)(tileA + (jt * 128 + lane * 2));  // linear by lane: conflict-free
        f16x4 af = __builtin_bit_cast(f16x4, au);
        f32x4 dot = __builtin_amdgcn_mfma_f32_16x16x16f16(af, bf, (f32x4){0.f, 0.f, 0.f, 0.f}, 0, 0, 0);
        f32x4 sq4 = *(const f32x4*)&sqs[jt * 16 + h * 4];  // quarter-broadcast
        bool fired = false;
#pragma unroll
        for (int q = 0; q < 4; q++) {
            float d2 = fmaf(-2.0f, dot[q], sqi + sq4[q]);
            float d2c = fmaxf(d2, 0.0f);
            float d = sqrtf(d2c);
            s1 += d;
            s2 += d2c;
            unsigned u = __float_as_uint(d2c);
            if (u < Tg) {  // group-threshold filter
                fired = true;
#pragma unroll
                for (int c = 0; c < 15; c++) {
                    unsigned lo = umn(lst[c], u), hi = umx(lst[c], u);
                    lst[c] = lo; u = hi;
                }
                T = lst[14];
            }
        }
        if (__any(fired)) {  // wave-uniform refresh of group thresholds
            unsigned t1 = umn(T, (unsigned)__shfl_xor((int)T, 16));
            Tg = umn(t1, (unsigned)__shfl_xor((int)t1, 32));
        }
    }
    // sums over the 4 lanes sharing i
    s1 += __shfl_xor(s1, 16); s1 += __shfl_xor(s1, 32);
    s2 += __shfl_xor(s2, 16); s2 += __shfl_xor(s2, 32);
    if (h == 0) {
        s1p[(size_t)i * CH + chunk] = s1;
        s2p[(size_t)i * CH + chunk] = s2;
    }
    // merge 4 sorted 15-lists per i -> chunk top-15 (tile is dead; alias as list buffer)
    __syncthreads();
    float* lw = (float*)tileA;  // 8*64*15 floats = 30720B <= 32KB
    {
        int base = (wid * 64 + lane) * 15;
#pragma unroll
        for (int c = 0; c < 15; c++) lw[base + c] = __uint_as_float(lst[c]);
    }
    __syncthreads();
    if (h == 0) {
        int b0 = (wid * 64 + lane) * 15;
        int b1 = b0 + 16 * 15, b2 = b0 + 32 * 15, b3 = b0 + 48 * 15;
        int p0 = 0, p1 = 0, p2 = 0, p3 = 0;
        float* dst = smlp + ((size_t)i * CH + chunk) * 15;
        for (int rr = 0; rr < 15; rr++) {
            float v0 = (p0 < 15) ? lw[b0 + p0] : FLT_MAX;
            float v1 = (p1 < 15) ? lw[b1 + p1] : FLT_MAX;
            float v2 = (p2 < 15) ? lw[b2 + p2] : FLT_MAX;
            float v3 = (p3 < 15) ? lw[b3 + p3] : FLT_MAX;
            float m = fminf(fminf(v0, v1), fminf(v2, v3));
            if (v0 == m) p0++; else if (v1 == m) p1++; else if (v2 == m) p2++; else p3++;
            dst[rr] = m;
        }
    }
}

// ---------------- merge1: density + global top-15 (one wave per row) ----------------
__global__ __launch_bounds__(512) void k_merge1(const float* __restrict__ s1p,
                                                const float* __restrict__ s2p,
                                                const float* __restrict__ smlp,
                                                float* __restrict__ den,
                                                float* __restrict__ sml) {
    const int tid = threadIdx.x, wid = tid >> 6, lane = tid & 63;
    const int i = blockIdx.x * 8 + wid;
    double g1 = 0.0, g2 = 0.0;
    if (lane < CH) {
        g1 = (double)s1p[(size_t)i * CH + lane];
        g2 = (double)s2p[(size_t)i * CH + lane];
    }
#pragma unroll
    for (int off = 1; off < 8; off <<= 1) {
        g1 += __shfl_xor(g1, off);
        g2 += __shfl_xor(g2, off);
    }
    if (lane == 0) {
        double var = (g2 - g1 * g1 / (double)NN) / (double)(NN - 1);
        den[i] = (float)sqrt(var > 0.0 ? var : 0.0);
    }
    // top-15 of the 120 chunk candidates
    const float* src = smlp + (size_t)i * (CH * 15);
    float v0 = src[lane];
    float v1 = (lane < CH * 15 - 64) ? src[lane + 64] : FLT_MAX;
    float lo = fminf(v0, v1), hi = fmaxf(v0, v1);
    int idx = 0;
    for (int rr = 0; rr < 15; rr++) {
        float cand = (idx == 0) ? lo : ((idx == 1) ? hi : FLT_MAX);
        float m = cand;
#pragma unroll
        for (int off = 1; off < 64; off <<= 1) m = fminf(m, __shfl_xor(m, off));
        unsigned long long b = __ballot(cand == m);
        if (lane == (int)(__ffsll(b) - 1)) idx++;
        if (lane == 0) sml[(size_t)i * 15 + rr] = m;
    }
}

// ---------------- global adaptive k ----------------
__global__ __launch_bounds__(1024) void k_adaptk(const float* __restrict__ density,
                                                 int* __restrict__ kout) {
    const int tid = threadIdx.x;
    __shared__ float redf[16];
    __shared__ int redi[16];
    __shared__ float dmax_sh;
    const int wid = tid >> 6, lane = tid & 63;
    float mx = 0.f;
    for (int r = tid; r < NN; r += 1024) mx = fmaxf(mx, density[r]);
#pragma unroll
    for (int off = 1; off < 64; off <<= 1) mx = fmaxf(mx, __shfl_xor(mx, off));
    if (lane == 0) redf[wid] = mx;
    __syncthreads();
    if (tid == 0) {
        float m = redf[0];
        for (int w = 1; w < 16; w++) m = fmaxf(m, redf[w]);
        dmax_sh = m;
    }
    __syncthreads();
    const float dmax = dmax_sh + EPSF;
    int ks = 0;
    for (int r = tid; r < NN; r += 1024) {
        float f = density[r] / dmax;
        float kf = fminf(fmaxf(5.0f + 10.0f * f, 5.0f), 20.0f);
        ks += (int)kf;
    }
#pragma unroll
    for (int off = 1; off < 64; off <<= 1) ks += __shfl_xor(ks, off);
    if (lane == 0) redi[wid] = ks;
    __syncthreads();
    if (tid == 0) {
        int t = 0;
        for (int w = 0; w < 16; w++) t += redi[w];
        float meank = (float)t / (float)NN;
        kout[0] = (int)meank;
    }
}

// ---------------- drift (MFMA QK + MFMA PV): partial numerator/wsum per chunk ----------------
__global__ __launch_bounds__(512, 2) void k_drift_mfma(const uint32_t* __restrict__ xch,
                                                       const float* __restrict__ sqh,
                                                       const float* __restrict__ sml,
                                                       const int* __restrict__ kptr,
                                                       float* __restrict__ nump,
                                                       float* __restrict__ wsp) {
    __shared__ uint32_t tileA[8 * 512];    // frag-order, 16KB
    __shared__ uint32_t tileT[16 * 256];   // transposed [d][jpair] with +2d rotation, 16KB
    __shared__ float sqs[512];             // 2KB
    const int tid = threadIdx.x, wid = tid >> 6, lane = tid & 63;
    const int r = lane & 15, h = lane >> 4;
    const int iG = blockIdx.x >> 3, chunk = blockIdx.x & 7;
    const int i0 = (iG * 8 + wid) << 4;
    const int i = i0 + r;

    const int k = kptr[0];
    const float sig2 = sml[(size_t)i * 15 + (k - 1)];  // k-th smallest d2 == sigma^2
    const float ninv = -1.0f / (2.0f * sig2 + EPSF);
    uint2 bu = *(const uint2*)(xch + (size_t)i * 8 + h * 2);
    f16x4 bf = __builtin_bit_cast(f16x4, bu);
    const float sqi = sqh[i];

    f32x4 acc = {0.f, 0.f, 0.f, 0.f};
    float ws = 0.f;

#pragma unroll 1
    for (int half = 0; half < 2; half++) {
        const int jb = (chunk << 10) + (half << 9);
        {
            int jl = tid;  // 0..511: one row each, frag-order
            const uint4* src = (const uint4*)(xch + (size_t)(jb + jl) * 8);
            uint4 a = src[0], b = src[1];
            uint32_t* base = tileA + ((jl >> 4) * 128 + (jl & 15) * 2);
            *(uint2*)(base)      = make_uint2(a.x, a.y);
            *(uint2*)(base + 32) = make_uint2(a.z, a.w);
            *(uint2*)(base + 64) = make_uint2(b.x, b.y);
            *(uint2*)(base + 96) = make_uint2(b.z, b.w);
            sqs[jl] = sqh[jb + jl];
            if (tid < 256) {  // transpose staging: j-pair per thread
                int jp = tid;
                const uint4* sA = (const uint4*)(xch + (size_t)(jb + 2 * jp) * 8);
                const uint4* sB = (const uint4*)(xch + (size_t)(jb + 2 * jp + 1) * 8);
                uint4 a0 = sA[0], a1 = sA[1], b0 = sB[0], b1 = sB[1];
                uint32_t rA[8] = {a0.x, a0.y, a0.z, a0.w, a1.x, a1.y, a1.z, a1.w};
                uint32_t rB[8] = {b0.x, b0.y, b0.z, b0.w, b1.x, b1.y, b1.z, b1.w};
#pragma unroll
                for (int d = 0; d < 16; d++) {
                    uint32_t lo = (d & 1) ? (rA[d >> 1] >> 16) : (rA[d >> 1] & 0xFFFFu);
                    uint32_t hi = (d & 1) ? (rB[d >> 1] & 0xFFFF0000u) : (rB[d >> 1] << 16);
                    tileT[d * 256 + ((jp + 2 * d) & 255)] = lo | hi;
                }
            }
        }
        __syncthreads();
        for (int jt = 0; jt < 32; jt++) {
            uint2 au = *(const uint2*)(tileA + (jt * 128 + lane * 2));
            f16x4 af = __builtin_bit_cast(f16x4, au);
            f32x4 dot = __builtin_amdgcn_mfma_f32_16x16x16f16(af, bf, (f32x4){0.f, 0.f, 0.f, 0.f}, 0, 0, 0);
            f32x4 sq4 = *(const f32x4*)&sqs[jt * 16 + h * 4];
            float w0, w1, w2, w3;
            {
                float d2, d;
                d2 = fmaf(-2.f, dot[0], sqi + sq4[0]); d = sqrtf(fmaxf(d2, 0.f)); w0 = __expf(d * ninv);
                d2 = fmaf(-2.f, dot[1], sqi + sq4[1]); d = sqrtf(fmaxf(d2, 0.f)); w1 = __expf(d * ninv);
                d2 = fmaf(-2.f, dot[2], sqi + sq4[2]); d = sqrtf(fmaxf(d2, 0.f)); w2 = __expf(d * ninv);
                d2 = fmaf(-2.f, dot[3], sqi + sq4[3]); d = sqrtf(fmaxf(d2, 0.f)); w3 = __expf(d * ninv);
            }
            ws += (w0 + w1) + (w2 + w3);
            // W tile (C layout) == A-frag layout for PV: q <-> b, no cross-lane movement
            uint2 wp = make_uint2(pkrtz(w0, w1), pkrtz(w2, w3));
            f16x4 wf = __builtin_bit_cast(f16x4, wp);
            // B = Xc^T: lane l: n=d=r, k=j = jt*16 + 4h + [0..3] -> j-pairs jt*8+2h+{0,1}, rotated
            int jp0 = jt * 8 + h * 2;
            uint2 tv = *(const uint2*)(tileT + (r * 256 + ((jp0 + 2 * r) & 255)));
            f16x4 btf = __builtin_bit_cast(f16x4, tv);
            acc = __builtin_amdgcn_mfma_f32_16x16x16f16(wf, btf, acc, 0, 0, 0);
        }
        __syncthreads();
    }
    ws += __shfl_xor(ws, 16); ws += __shfl_xor(ws, 32);
    if (h == 0) wsp[(size_t)i * CH + chunk] = ws;
    // acc: D[m=i_local= h*4+q][n=d=r]
#pragma unroll
    for (int q = 0; q < 4; q++) {
        int irow = i0 + h * 4 + q;
        nump[((size_t)irow * CH + chunk) * 16 + r] = acc[q];
    }
}

// ---------------- merge drift partials ----------------
__global__ __launch_bounds__(256) void k_merge_drift(const float* __restrict__ nump,
                                                     const float* __restrict__ wsp,
                                                     float* __restrict__ drf) {
    const int t = blockIdx.x * 256 + threadIdx.x;  // < NN*16
    const int i = t >> 4, d = t & 15;
    float s = 0.f;
#pragma unroll
    for (int c = 0; c < CH; c++) s += nump[((size_t)i * CH + c) * 16 + d];
    float w = 0.f;
#pragma unroll
    for (int c = 0; c < CH; c++) w += wsp[(size_t)i * CH + c];
    drf[t] = s / (w + EPSF);
}

// ---------------- fused: h = xc + step*(drift-xc) + 0.01*noise; col-stat partials ----------------
__global__ __launch_bounds__(256) void k_hpre_stats(const float* __restrict__ xc,
                                                    const float* __restrict__ drift,
                                                    const float* __restrict__ noise,
                                                    const float* __restrict__ alpha,
                                                    float* __restrict__ hpre,
                                                    double* __restrict__ part) {
    const int i = blockIdx.x * 256 + threadIdx.x;
    const float step = powf(16.0f, -alpha[0]);
    const f4* xr = (const f4*)(xc + (size_t)i * DD);
    const f4* dr = (const f4*)(drift + (size_t)i * DD);
    const f4* nr = (const f4*)(noise + (size_t)i * DD);
    f4* ho = (f4*)(hpre + (size_t)i * DD);
    float h[DD];
#pragma unroll
    for (int q = 0; q < 4; q++) {
        f4 a = xr[q], b = dr[q], n = nr[q], o;
        o.x = a.x + step * (b.x - a.x) + n.x * 0.01f;
        o.y = a.y + step * (b.y - a.y) + n.y * 0.01f;
        o.z = a.z + step * (b.z - a.z) + n.z * 0.01f;
        o.w = a.w + step * (b.w - a.w) + n.w * 0.01f;
        ho[q] = o;
        h[4*q+0] = o.x; h[4*q+1] = o.y; h[4*q+2] = o.z; h[4*q+3] = o.w;
    }
    colstat_reduce_store(h, part, blockIdx.x, threadIdx.x);
}

__global__ __launch_bounds__(64) void k_stats_fin2(const double* __restrict__ part,
                                                   const float* __restrict__ stdx,
                                                   float* __restrict__ ratio) {
    const int c = threadIdx.x;
    if (c < DD) {
        double s = 0.0, q = 0.0;
        for (int b = 0; b < 32; b++) {
            s += part[(size_t)b * 2 * DD + c];
            q += part[(size_t)b * 2 * DD + DD + c];
        }
        double var = (q - s * s / (double)NN) / (double)(NN - 1);
        float stdh = (float)sqrt(var > 0.0 ? var : 0.0);
        ratio[c] = stdx[c] / (stdh + EPSF);
    }
}

// ---------------- final: out = h * ratio + mean (in place) ----------------
__global__ __launch_bounds__(256) void k_final(float* __restrict__ h,
                                               const float* __restrict__ ratio,
                                               const float* __restrict__ meanp) {
    const int i = blockIdx.x * 256 + threadIdx.x;
    const f4* rr = (const f4*)ratio;
    const f4* mr = (const f4*)meanp;
    f4* hr = (f4*)(h + (size_t)i * DD);
#pragma unroll
    for (int q = 0; q < 4; q++) {
        f4 v = hr[q], rv = rr[q], mv = mr[q];
        v.x = v.x * rv.x + mv.x;
        v.y = v.y * rv.y + mv.y;
        v.z = v.z * rv.z + mv.z;
        v.w = v.w * rv.w + mv.w;
        hr[q] = v;
    }
}

extern "C" void kernel_launch(void* const* d_in, const int* in_sizes, int n_in,
                              void* d_out, int out_size, void* d_ws, size_t ws_size,
                              hipStream_t stream) {
    (void)in_sizes; (void)n_in; (void)out_size; (void)ws_size;
    const float* x = (const float*)d_in[0];
    const float* noise = (const float*)d_in[1];
    const float* alpha = (const float*)d_in[2];
    float* out = (float*)d_out;

    double* part1 = (double*)d_ws;                        // 1024 dbl
    double* part2 = part1 + 1024;                         // 1024 dbl
    float*    xc   = (float*)(part2 + 1024);              // N*16
    uint32_t* xch  = (uint32_t*)(xc + (size_t)NN * DD);   // N*8
    float*    sqh  = (float*)(xch + (size_t)NN * 8);      // N
    float*    den  = sqh + NN;                            // N
    float*    s1p  = den + NN;                            // N*8
    float*    s2p  = s1p + (size_t)NN * CH;               // N*8
    float*    smlp = s2p + (size_t)NN * CH;               // N*8*15
    float*    sml  = smlp + (size_t)NN * CH * 15;         // N*15
    float*    nump = sml + (size_t)NN * 15;               // N*8*16
    float*    wsp  = nump + (size_t)NN * CH * 16;         // N*8
    float*    drf  = wsp + (size_t)NN * CH;               // N*16
    float*    meanp = drf + (size_t)NN * DD;              // 16
    float*    stdx  = meanp + DD;                         // 16
    float*    ratio = stdx + DD;                          // 16
    int*      kptr  = (int*)(ratio + DD);                 // 1

    k_stats_part_x<<<32, 256, 0, stream>>>(x, part1);
    k_stats_fin1<<<1, 64, 0, stream>>>(part1, meanp, stdx);
    k_center<<<32, 256, 0, stream>>>(x, meanp, xc, xch, sqh);
    k_pass1_mfma<<<512, 512, 0, stream>>>(xch, sqh, s1p, s2p, smlp);
    k_merge1<<<NN / 8, 512, 0, stream>>>(s1p, s2p, smlp, den, sml);
    k_adaptk<<<1, 1024, 0, stream>>>(den, kptr);
    k_drift_mfma<<<512, 512, 0, stream>>>(xch, sqh, sml, kptr, nump, wsp);
    k_merge_drift<<<NN * DD / 256, 256, 0, stream>>>(nump, wsp, drf);
    k_hpre_stats<<<32, 256, 0, stream>>>(xc, drf, noise, alpha, out, part2);
    k_stats_fin2<<<1, 64, 0, stream>>>(part2, stdx, ratio);
    k_final<<<32, 256, 0, stream>>>(out, ratio, meanp);
}